// Round 6
// baseline (254.497 us; speedup 1.0000x reference)
//
#include <hip/hip_runtime.h>
#include <cstdint>
#include <cstddef>

// Problem constants
constexpr int NPTS    = 65536;
constexpr int B       = 256;
constexpr int CHUNKS  = 8;              // stream blocks per row
constexpr int CHUNK   = NPTS / CHUNKS;  // 8192 elements
constexpr int CCAP    = 256;            // per-chunk candidate cap (mean 82, sigma 9)
constexpr int NBLK    = B * CHUNKS;     // 2048 stream blocks
constexpr int NEARCAP = 128;            // near-max list cap per row-sign (mean ~36)

// Workspace layout (word offsets; u64 regions first => 8-byte aligned)
constexpr size_t WSO_CBUF    = 0;                                      // NBLK*CCAP u64
constexpr size_t WSO_NEAR    = WSO_CBUF + (size_t)NBLK * CCAP * 2;     // 2*B*NEARCAP u64
// ---- contiguous zero-initialized strip (one hipMemsetAsync) ----
constexpr size_t WSO_ZERO    = WSO_NEAR + (size_t)2 * B * NEARCAP * 2;
constexpr size_t WSO_NEARCNT = WSO_ZERO;                               // 2*B ints
constexpr size_t WSO_ROWDONE = WSO_NEARCNT + 2 * B;                    // B ints
constexpr size_t WSO_R3DONE  = WSO_ROWDONE + B;                        // B ints
constexpr size_t WSO_SUMP    = WSO_R3DONE + B;                         // B floats (atomic)
constexpr size_t WSO_PMAXP   = WSO_SUMP + B;                           // B uints (atomicMax)
constexpr size_t WSO_PMAXN   = WSO_PMAXP + B;                          // B uints
constexpr size_t WSO_ZEROEND = WSO_PMAXN + B;                          // strip = 7*B words
// ---- rest (always overwritten before read) ----
constexpr size_t WSO_CCNT    = WSO_ZEROEND;                            // NBLK ints
constexpr size_t WSO_PLANE   = WSO_CCNT + NBLK;                        // B floats
constexpr size_t WSO_FACET   = WSO_PLANE + B;                          // B floats
constexpr size_t WSO_NRM     = WSO_FACET + B;                          // B*8 floats
constexpr size_t WSO_ANORM   = WSO_NRM + (size_t)B * 8;                // B floats
constexpr size_t WSO_T64V    = WSO_ANORM + B;                          // B*64 floats
constexpr size_t WSO_T64I    = WSO_T64V + (size_t)B * 64;              // B*64 ints
// total ~4.8 MB

__device__ __forceinline__ float clipp(float x) {
    return fminf(fmaxf(x, 1e-5f), 0.99999f);
}
__device__ __forceinline__ unsigned f2mono(float f) {
    unsigned u = __float_as_uint(f);
    return (u & 0x80000000u) ? ~u : (u | 0x80000000u);
}
__device__ __forceinline__ float mono2f(unsigned e) {
    return __uint_as_float((e & 0x80000000u) ? (e ^ 0x80000000u) : ~e);
}
__device__ __forceinline__ int cand_bin(float v) {
    int b = (int)((v - 0.99f) * 102400.0f);   // 1024 bins over [0.99, 1.0)
    return min(max(b, 0), 1023);
}
__device__ __forceinline__ float dot8(float4 a, float4 b, const float* n) {
    float d = a.x * n[0];
    d = fmaf(a.y, n[1], d); d = fmaf(a.z, n[2], d); d = fmaf(a.w, n[3], d);
    d = fmaf(b.x, n[4], d); d = fmaf(b.y, n[5], d); d = fmaf(b.z, n[6], d);
    d = fmaf(b.w, n[7], d);
    return d;
}
// agent-scope (device-coherent) helpers: data crossing XCD boundaries goes
// through the coherence point; no L2-writeback fence needed (G16).
__device__ __forceinline__ void ast_u64(unsigned long long* p, unsigned long long v) {
    __hip_atomic_store(p, v, __ATOMIC_RELAXED, __HIP_MEMORY_SCOPE_AGENT);
}
__device__ __forceinline__ unsigned long long ald_u64(const unsigned long long* p) {
    return __hip_atomic_load(p, __ATOMIC_RELAXED, __HIP_MEMORY_SCOPE_AGENT);
}
__device__ __forceinline__ void ast_i32(int* p, int v) {
    __hip_atomic_store(p, v, __ATOMIC_RELAXED, __HIP_MEMORY_SCOPE_AGENT);
}
__device__ __forceinline__ int ald_i32(const int* p) {
    return __hip_atomic_load(p, __ATOMIC_RELAXED, __HIP_MEMORY_SCOPE_AGENT);
}
__device__ __forceinline__ unsigned ald_u32(const unsigned* p) {
    return __hip_atomic_load(p, __ATOMIC_RELAXED, __HIP_MEMORY_SCOPE_AGENT);
}

// ---------------------------------------------------------------------------
// K1: fused stream + per-row selection. 2048 blocks x 256 threads.
// Phase A (all blocks): stream one 8192-elem chunk of prob — clipped sum +
// candidate (>=0.99) append to the chunk's global buffer.
// Phase B (the 8th/last block of each row, via agent-scope done-counter):
// exact top-128/top-64 sets (hist + rank-select, no sort), weighted moments,
// and the 64-lane element-parallel tournament Jacobi. Per-row selection
// overlaps other rows' streaming; kills one launch + grid-wide drain.
__global__ __launch_bounds__(256) void k1_stream_select(
    const float* __restrict__ prob, const float* __restrict__ points,
    float* __restrict__ ws)
{
    __shared__ unsigned long long cand[CHUNKS * CCAP];  // 16 KB
    __shared__ unsigned long long comp[256];
    __shared__ int   hist[1024];
    __shared__ int   counts_s[CHUNKS];
    __shared__ int   ccnt_s, bt_s, last_s, lcnt;
    __shared__ float sw[128];
    __shared__ float pc[128][9];                        // col 8 == 1.0f
    __shared__ float sred[44][4];
    __shared__ float slotm[44];
    __shared__ float wpart[2];
    __shared__ float covm[64];
    __shared__ float wred[4];

    const int tid   = threadIdx.x;
    const int row   = blockIdx.x >> 3;
    const int chunk = blockIdx.x & 7;
    if (tid == 0) lcnt = 0;
    __syncthreads();

    // ---------------- phase A: stream ----------------
    unsigned long long* cb0 = (unsigned long long*)ws + (size_t)blockIdx.x * CCAP;
    const float4* p4 = (const float4*)(prob + (size_t)row * NPTS + (size_t)chunk * CHUNK);
    float lsum = 0.f;
    #pragma unroll
    for (int i = 0; i < CHUNK / 4 / 256; i++) {        // 8 iterations
        float4 v = p4[i * 256 + tid];
        float c0 = clipp(v.x), c1 = clipp(v.y), c2 = clipp(v.z), c3 = clipp(v.w);
        lsum += (c0 + c1) + (c2 + c3);
        float mx = fmaxf(fmaxf(c0, c1), fmaxf(c2, c3));
        if (mx >= 0.99f) {                             // rare path (~3.9% of quads)
            int bi = chunk * CHUNK + (i * 256 + tid) * 4;
            float c4[4] = {c0, c1, c2, c3};
            #pragma unroll
            for (int j = 0; j < 4; j++) {
                if (c4[j] >= 0.99f) {
                    int p_ = atomicAdd(&lcnt, 1);
                    if (p_ < CCAP)
                        ast_u64(&cb0[p_],
                            (((unsigned long long)__float_as_uint(c4[j])) << 32)
                            | (unsigned)~(bi + j));
                }
            }
        }
    }
    #pragma unroll
    for (int off = 32; off; off >>= 1) lsum += __shfl_down(lsum, off);
    if ((tid & 63) == 0) wred[tid >> 6] = lsum;
    __syncthreads();                                   // drains all cb0 stores too
    if (tid == 0) {
        atomicAdd(&ws[WSO_SUMP + row], (wred[0] + wred[1]) + (wred[2] + wred[3]));
        ast_i32((int*)ws + WSO_CCNT + blockIdx.x, min(lcnt, CCAP));
        int old = __hip_atomic_fetch_add((int*)ws + WSO_ROWDONE + row, 1,
                                         __ATOMIC_ACQ_REL, __HIP_MEMORY_SCOPE_AGENT);
        last_s = (old == CHUNKS - 1);
    }
    __syncthreads();
    if (!last_s) return;                               // whole block exits together

    // ---------------- phase B: selection for `row` ----------------
    if (tid < CHUNKS) counts_s[tid] = ald_i32((int*)ws + WSO_CCNT + row * CHUNKS + tid);
    if (tid == 0) { ccnt_s = 0; bt_s = 0; }
    #pragma unroll
    for (int k = 0; k < 4; k++) hist[tid * 4 + k] = 0;
    __syncthreads();

    // fixed-stride gather + histogram
    const unsigned long long* cb = (const unsigned long long*)ws;
    #pragma unroll
    for (int r = 0; r < CHUNKS; r++) {
        int s = r * 256 + tid;
        int c = s >> 8, t = s & 255;
        unsigned long long k = 0ull;
        if (t < counts_s[c]) {
            k = ald_u64(&cb[((size_t)(row * CHUNKS + c) << 8) + t]);
            atomicAdd(&hist[cand_bin(__uint_as_float((unsigned)(k >> 32)))], 1);
        }
        cand[s] = k;
    }
    __syncthreads();

    // threshold bin via one wave: suffix-scan 64 groups of 16 bins
    if (tid < 64) {
        int h[16]; int g = 0;
        #pragma unroll
        for (int k = 0; k < 16; k++) { h[k] = hist[tid * 16 + k]; g += h[k]; }
        int s = g;
        #pragma unroll
        for (int off = 1; off < 64; off <<= 1) {
            int o = __shfl_down(s, off);
            if (tid + off < 64) s += o;
        }
        int Snext = __shfl_down(s, 1);
        if (tid == 63) Snext = 0;
        if (s >= 128 && Snext < 128) {   // exactly one lane
            int acc = Snext, bt = tid * 16;
            #pragma unroll
            for (int k = 15; k >= 0; k--) {
                acc += h[k];
                if (acc >= 128) { bt = tid * 16 + k; break; }
            }
            bt_s = bt;
        }
    }
    __syncthreads();

    // compact survivors (bin >= bt); m in [128, ~140]
    const int bt = bt_s;
    #pragma unroll
    for (int r = 0; r < CHUNKS; r++) {
        unsigned long long k = cand[r * 256 + tid];
        if (k && cand_bin(__uint_as_float((unsigned)(k >> 32))) >= bt) {
            int p_ = atomicAdd(&ccnt_s, 1);
            if (p_ < 256) comp[p_] = k;
        }
    }
    __syncthreads();
    const int m = min(ccnt_s, 256);

    if (tid < 128) {
        sw[tid] = 0.f;
        #pragma unroll
        for (int j = 0; j < 9; j++) pc[tid][j] = (j == 8) ? 1.f : 0.f;
    }
    if (tid < 64) {
        ws[WSO_T64V + (size_t)row * 64 + tid] = 0.f;
        ((int*)ws)[WSO_T64I + (size_t)row * 64 + tid] = 0;
    }
    // rank of each survivor vs all m keys (broadcast LDS reads, unique keys)
    unsigned long long ki = (tid < m) ? comp[tid] : 0ull;
    int rank = 0;
    for (int j = 0; j < m; j++) rank += (comp[j] > ki) ? 1 : 0;
    __syncthreads();

    // scatter by rank: slots 0..127 = exact top-128 (rank order = lax.top_k order)
    if (tid < m && rank < 128) {
        float v = __uint_as_float((unsigned)(ki >> 32));
        unsigned idx = ~(unsigned)(ki & 0xFFFFFFFFu);
        sw[rank] = v;
        const float4* pt = (const float4*)(points + (size_t)idx * 8);
        float4 q0 = pt[0], q1 = pt[1];
        pc[rank][0] = q0.x; pc[rank][1] = q0.y; pc[rank][2] = q0.z; pc[rank][3] = q0.w;
        pc[rank][4] = q1.x; pc[rank][5] = q1.y; pc[rank][6] = q1.z; pc[rank][7] = q1.w;
        if (rank < 64) {
            ws[WSO_T64V + (size_t)row * 64 + rank] = v;
            ((int*)ws)[WSO_T64I + (size_t)row * 64 + rank] = (int)idx;
        }
    }
    __syncthreads();

    if (tid < 128) {
        float ww = sw[tid];
        #pragma unroll
        for (int off = 32; off; off >>= 1) ww += __shfl_down(ww, off);
        if ((tid & 63) == 0) wpart[tid >> 6] = ww;
    }
    // moments: 44 slots x 4 partials (tid < 176)
    if (tid < 176) {
        int s = tid >> 2, part = tid & 3;
        int i_, j_;
        if (s < 36) {
            int rem = s; i_ = 0;
            while (rem >= 8 - i_) { rem -= 8 - i_; i_++; }
            j_ = i_ + rem;
        } else { i_ = s - 36; j_ = 8; }
        float acc = 0.f;
        for (int k = part * 32; k < part * 32 + 32; k++)
            acc += sw[k] * pc[k][i_] * pc[k][j_];
        sred[s][part] = acc;
    }
    __syncthreads();
    if (tid < 44) slotm[tid] = (sred[tid][0] + sred[tid][1]) + (sred[tid][2] + sred[tid][3]);
    __syncthreads();

    if (tid < 64) {
        float w128 = fmaxf(wpart[0] + wpart[1], 1e-6f);
        int i_ = tid >> 3, j_ = tid & 7;
        int a_ = min(i_, j_), b_ = max(i_, j_);
        int s3 = 8 * a_ - (a_ * (a_ - 1)) / 2 + (b_ - a_);
        covm[tid] = slotm[s3] / w128 - (slotm[36 + i_] / w128) * (slotm[36 + j_] / w128);
    }
    if (tid == 64) ws[WSO_ANORM + row] = fmaxf(wpart[0], 1e-6f);
    __syncthreads();

    // ---- element-parallel Jacobi (wave 0; lane = i*8+j owns A[i][j]) ----
    if (tid < 64) {
        const int i = tid >> 3, j = tid & 7;
        float a = covm[tid];
        float v = (i == j) ? 1.f : 0.f;
        // round-robin tournament pairings; octal digit i = partner(i)
        const unsigned PR[7] = {023456701u, 001234567u, 050712346u, 034067125u,
                                012305674u, 067120453u, 045671032u};
        #pragma unroll 1
        for (int sweep = 0; sweep < 6; sweep++) {
            #pragma unroll
            for (int r = 0; r < 7; r++) {
                const unsigned pk = PR[r];
                const int rp = (pk >> (3 * i)) & 7;       // row-pair partner
                const int cp = (pk >> (3 * j)) & 7;       // col-pair partner
                const int pr = min(i, rp), qr = max(i, rp);
                float app = __shfl(a, pr * 9);
                float aqq = __shfl(a, qr * 9);
                float apq = __shfl(a, pr * 8 + qr);
                float tau = 0.5f * (aqq - app);
                float den = fabsf(tau) + sqrtf(fmaf(tau, tau, apq * apq));
                float t = __fdividef(apq, den + 1e-38f);  // apq==0 -> identity
                t = (tau < 0.f) ? -t : t;
                float cr = rsqrtf(fmaf(t, t, 1.f));
                float sr = t * cr;
                float cc = __shfl(cr, j * 9);
                float sc = __shfl(sr, j * 9);
                float oth = __shfl(a, rp * 8 + j);        // row phase (J^T A)
                a = fmaf((i < rp) ? -sr : sr, oth, cr * a);
                float oth2 = __shfl(a, i * 8 + cp);       // col phase (A J)
                a = fmaf((j < cp) ? -sc : sc, oth2, cc * a);
                float ov = __shfl(v, i * 8 + cp);
                v = fmaf((j < cp) ? -sc : sc, ov, cc * v);
            }
        }
        float d[8];
        #pragma unroll
        for (int k = 0; k < 8; k++) d[k] = __shfl(a, k * 9);
        float e0 = d[0]; int i0 = 0;
        #pragma unroll
        for (int k = 1; k < 8; k++) if (d[k] < e0) { e0 = d[k]; i0 = k; }
        float e1 = 3.4e38f;
        #pragma unroll
        for (int k = 0; k < 8; k++) if (k != i0 && d[k] < e1) e1 = d[k];
        if (tid == 0) {
            ws[WSO_PLANE + row] = e0;
            ws[WSO_FACET + row] = e0 / (e1 + 1e-6f);
        }
        if (j == i0) ws[WSO_NRM + (size_t)row * 8 + i] = v;   // V[:,i0]
        // eigenvector sign arbitrary: boundary = min(b_pos, b_neg) is sign-invariant
    }
}

// ---------------------------------------------------------------------------
// K2: fused proj-max + near-max collection + per-row finalize.
// Phase A (all blocks): 4 rows x 2048 points; row maxes (atomicMax) + near-max
// candidates (d >= blockmax-0.05 superset) to global lists.
// Phase B (32nd/last block per row, wave 0): active term over top-64 +
// inactive term over the ~36-entry near list + final combine.
constexpr int R3 = 4;
constexpr int P3 = 2048;
__global__ __launch_bounds__(256) void k2_max_final(
    const float* __restrict__ points, const float* __restrict__ prob,
    float* __restrict__ ws, float* __restrict__ out)
{
    __shared__ float redp[4][R3], redn[4][R3];
    __shared__ float bmax[2 * R3];
    __shared__ int   flag[R3];
    const int tid = threadIdx.x;
    const int r0  = blockIdx.y * R3;
    const int n0  = blockIdx.x * P3;
    float nr[R3][8];
    #pragma unroll
    for (int r = 0; r < R3; r++)
        #pragma unroll
        for (int j = 0; j < 8; j++)
            nr[r][j] = ws[WSO_NRM + (size_t)(r0 + r) * 8 + j];
    float dsv[P3 / 256][R3];
    float mp[R3], mn[R3];
    #pragma unroll
    for (int r = 0; r < R3; r++) { mp[r] = -3.4e38f; mn[r] = -3.4e38f; }
    const float4* pb = (const float4*)points + (size_t)n0 * 2;
    #pragma unroll
    for (int it = 0; it < P3 / 256; it++) {
        int t2 = (it * 256 + tid) * 2;
        float4 q0 = pb[t2], q1 = pb[t2 + 1];
        #pragma unroll
        for (int r = 0; r < R3; r++) {
            float d = dot8(q0, q1, nr[r]);
            dsv[it][r] = d;
            mp[r] = fmaxf(mp[r], d);
            mn[r] = fmaxf(mn[r], -d);
        }
    }
    #pragma unroll
    for (int r = 0; r < R3; r++) {
        #pragma unroll
        for (int off = 32; off; off >>= 1) {
            mp[r] = fmaxf(mp[r], __shfl_xor(mp[r], off));
            mn[r] = fmaxf(mn[r], __shfl_xor(mn[r], off));
        }
    }
    if ((tid & 63) == 0) {
        int wv = tid >> 6;
        #pragma unroll
        for (int r = 0; r < R3; r++) { redp[wv][r] = mp[r]; redn[wv][r] = mn[r]; }
    }
    __syncthreads();
    if (tid < 2 * R3) {
        int r = tid & (R3 - 1);
        bool neg = tid >= R3;
        float m = neg
            ? fmaxf(fmaxf(redn[0][r], redn[1][r]), fmaxf(redn[2][r], redn[3][r]))
            : fmaxf(fmaxf(redp[0][r], redp[1][r]), fmaxf(redp[2][r], redp[3][r]));
        bmax[tid] = m;
        unsigned* wsu = (unsigned*)ws;
        atomicMax(&wsu[(neg ? WSO_PMAXN : WSO_PMAXP) + r0 + r], f2mono(m));
    }
    __syncthreads();
    float bmx[R3], bmn[R3];
    #pragma unroll
    for (int r = 0; r < R3; r++) { bmx[r] = bmax[r]; bmn[r] = bmax[R3 + r]; }

    // near-max candidates -> global per-row-sign lists (rare)
    int* ncnt = (int*)ws + WSO_NEARCNT;
    unsigned long long* nbuf = (unsigned long long*)ws + WSO_NEAR / 2;
    #pragma unroll
    for (int it = 0; it < P3 / 256; it++) {
        int nn = n0 + it * 256 + tid;
        #pragma unroll
        for (int r = 0; r < R3; r++) {
            float d = dsv[it][r];
            if (d >= bmx[r] - 0.05f) {
                int p_ = atomicAdd(&ncnt[(r0 + r) * 2 + 0], 1);
                if (p_ < NEARCAP)
                    ast_u64(&nbuf[(size_t)((r0 + r) * 2 + 0) * NEARCAP + p_],
                        (((unsigned long long)__float_as_uint(d)) << 32) | (unsigned)nn);
            }
            if (-d >= bmn[r] - 0.05f) {
                int p_ = atomicAdd(&ncnt[(r0 + r) * 2 + 1], 1);
                if (p_ < NEARCAP)
                    ast_u64(&nbuf[(size_t)((r0 + r) * 2 + 1) * NEARCAP + p_],
                        (((unsigned long long)__float_as_uint(-d)) << 32) | (unsigned)nn);
            }
        }
    }
    __syncthreads();                                   // drain nbuf stores
    if (tid < R3) {
        int old = __hip_atomic_fetch_add((int*)ws + WSO_R3DONE + r0 + tid, 1,
                                         __ATOMIC_ACQ_REL, __HIP_MEMORY_SCOPE_AGENT);
        flag[tid] = (old == (NPTS / P3) - 1) ? 1 : 0;
    }
    __syncthreads();
    if (tid >= 64) return;                             // finalize on wave 0 only
    const int t = tid;
    const unsigned* wsu = (const unsigned*)ws;
    for (int r = 0; r < R3; r++) {
        if (!flag[r]) continue;
        const int row = r0 + r;
        const float pmaxp = mono2f(ald_u32(&wsu[WSO_PMAXP + row]));
        const float pmaxn = mono2f(ald_u32(&wsu[WSO_PMAXN + row]));
        // active term over top-64 (written by K1, prior kernel -> plain loads ok)
        float w   = ws[WSO_T64V + (size_t)row * 64 + t];
        int   idx = ((const int*)ws)[WSO_T64I + (size_t)row * 64 + t];
        const float4* pt = (const float4*)(points + (size_t)idx * 8);
        float4 q0 = pt[0], q1 = pt[1];
        float d = dot8(q0, q1, nr[r]);
        float sp = d - pmaxp, sn = -d - pmaxn;
        float ap = w * sp * sp;
        float an = w * sn * sn;
        // inactive term from near-max lists (agent-scope reads)
        float ip = 0.f, in_ = 0.f;
        int cp = min(ald_i32(&ncnt[row * 2 + 0]), NEARCAP);
        int cn = min(ald_i32(&ncnt[row * 2 + 1]), NEARCAP);
        for (int i = t; i < cp; i += 64) {
            unsigned long long e = ald_u64(&nbuf[(size_t)(row * 2 + 0) * NEARCAP + i]);
            float dv = __uint_as_float((unsigned)(e >> 32));
            float tp = 0.05f + (dv - pmaxp);
            if (tp > 0.f) {
                float w2 = 1.0f - clipp(prob[(size_t)row * NPTS + (unsigned)(e & 0xFFFFFFFFu)]);
                ip = fmaf(w2 * tp, tp, ip);
            }
        }
        for (int i = t; i < cn; i += 64) {
            unsigned long long e = ald_u64(&nbuf[(size_t)(row * 2 + 1) * NEARCAP + i]);
            float dv = __uint_as_float((unsigned)(e >> 32));
            float tn = 0.05f + (dv - pmaxn);
            if (tn > 0.f) {
                float w2 = 1.0f - clipp(prob[(size_t)row * NPTS + (unsigned)(e & 0xFFFFFFFFu)]);
                in_ = fmaf(w2 * tn, tn, in_);
            }
        }
        #pragma unroll
        for (int off = 32; off; off >>= 1) {
            ap  += __shfl_down(ap, off);
            an  += __shfl_down(an, off);
            ip  += __shfl_down(ip, off);
            in_ += __shfl_down(in_, off);
        }
        if (t == 0) {
            float anorm = ws[WSO_ANORM + row];
            float sump  = ws[WSO_SUMP + row];
            float inorm = fmaxf((float)NPTS - sump, 1e-6f);
            float bp = (ap / anorm) + 0.35f * (ip / inorm);
            float bn = (an / anorm) + 0.35f * (in_ / inorm);
            float bd = (bp <= bn) ? bp : bn;
            float def = fmaxf(26.0f - sump, 0.f);
            out[row] = ws[WSO_PLANE + row] + 8.0f * ws[WSO_FACET + row]
                     + 4.0f * bd + 25.0f * def * def;
        }
    }
}

// ---------------------------------------------------------------------------
extern "C" void kernel_launch(void* const* d_in, const int* in_sizes, int n_in,
                              void* d_out, int out_size, void* d_ws, size_t ws_size,
                              hipStream_t stream) {
    const float* prob   = (const float*)d_in[0];  // (256, 65536) f32
    const float* points = (const float*)d_in[1];  // (65536, 8) f32
    float* out = (float*)d_out;                   // (256,) f32
    float* ws  = (float*)d_ws;                    // ~4.8 MB used

    // zero the counter/accumulator strip (7*B words = 7 KB) — capturable memset node
    hipMemsetAsync((char*)d_ws + WSO_ZERO * 4, 0,
                   (WSO_ZEROEND - WSO_ZERO) * 4, stream);
    k1_stream_select<<<NBLK, 256, 0, stream>>>(prob, points, ws);
    dim3 g2(NPTS / P3, B / R3);
    k2_max_final<<<g2, 256, 0, stream>>>(points, prob, ws, out);
}

// Round 8
// 154.550 us; speedup vs baseline: 1.6467x; 1.6467x over previous
//
#include <hip/hip_runtime.h>
#include <cstdint>
#include <cstddef>

// Problem constants
constexpr int NPTS   = 65536;
constexpr int B      = 256;
constexpr int CHUNKS = 8;              // chunks per row (stream phase)
constexpr int CHUNK  = NPTS / CHUNKS;  // 8192 elements
constexpr int CCAP   = 256;            // per-chunk cap (mean 82, sigma 9 -> +19 sigma)
constexpr int NBLK   = B * CHUNKS;     // 2048 stream blocks
constexpr int NEARCAP = 128;           // near-max list cap per row-sign (mean ~36)

// Workspace layout (word offsets; u64 regions first => 8-byte aligned)
constexpr size_t WSO_CBUF    = 0;                                      // NBLK*CCAP u64
constexpr size_t WSO_NEAR    = WSO_CBUF + (size_t)NBLK * CCAP * 2;     // 2*B*NEARCAP u64
constexpr size_t WSO_NEARCNT = WSO_NEAR + (size_t)2 * B * NEARCAP * 2; // 2*B ints
constexpr size_t WSO_PSUM    = WSO_NEARCNT + 2 * B;                    // NBLK floats
constexpr size_t WSO_CCNT    = WSO_PSUM + NBLK;                        // NBLK ints
constexpr size_t WSO_PLANE   = WSO_CCNT + NBLK;                        // B floats
constexpr size_t WSO_FACET   = WSO_PLANE + B;                          // B floats
constexpr size_t WSO_NRM     = WSO_FACET + B;                          // B*8 floats
constexpr size_t WSO_SUMP    = WSO_NRM + (size_t)B * 8;                // B floats
constexpr size_t WSO_ANORM   = WSO_SUMP + B;                           // B floats
constexpr size_t WSO_T64V    = WSO_ANORM + B;                          // B*64 floats
constexpr size_t WSO_T64I    = WSO_T64V + (size_t)B * 64;              // B*64 ints
constexpr size_t WSO_PMAXP   = WSO_T64I + (size_t)B * 64;              // B uints
constexpr size_t WSO_PMAXN   = WSO_PMAXP + B;                          // B uints
// total ~5 MB

using v4f = __attribute__((ext_vector_type(4))) float;   // nontemporal-compatible

__device__ __forceinline__ float clipp(float x) {
    return fminf(fmaxf(x, 1e-5f), 0.99999f);
}
__device__ __forceinline__ unsigned f2mono(float f) {
    unsigned u = __float_as_uint(f);
    return (u & 0x80000000u) ? ~u : (u | 0x80000000u);
}
__device__ __forceinline__ float mono2f(unsigned e) {
    return __uint_as_float((e & 0x80000000u) ? (e ^ 0x80000000u) : ~e);
}
__device__ __forceinline__ int cand_bin(float v) {
    int b = (int)((v - 0.99f) * 102400.0f);   // 1024 bins over [0.99, 1.0)
    return min(max(b, 0), 1023);
}
__device__ __forceinline__ float dot8(float4 a, float4 b, const float* n) {
    float d = a.x * n[0];
    d = fmaf(a.y, n[1], d); d = fmaf(a.z, n[2], d); d = fmaf(a.w, n[3], d);
    d = fmaf(b.x, n[4], d); d = fmaf(b.y, n[5], d); d = fmaf(b.z, n[6], d);
    d = fmaf(b.w, n[7], d);
    return d;
}

// ---------------------------------------------------------------------------
// kA: streaming pass over the 64 MB prob matrix at HBM rate.
// 2048 blocks x 256 threads, 32 elements/thread. Hot loop = nontemporal loads
// (read-once stream; keeps points/candidates cacheable in L2 for later
// kernels) + clips + sum + one fmax-tree predicate per float4; candidate
// append (~3.9% of quads) on the rare divergent path.
__global__ __launch_bounds__(256) void kA_stream(
    const float* __restrict__ prob, float* __restrict__ ws)
{
    __shared__ float wred[4];
    __shared__ int lcnt;
    const int tid   = threadIdx.x;
    const int row   = blockIdx.x >> 3;
    const int chunk = blockIdx.x & 7;
    if (tid == 0) lcnt = 0;
    __syncthreads();

    unsigned long long* cb = (unsigned long long*)ws + (size_t)blockIdx.x * CCAP;
    const v4f* p4 = (const v4f*)(prob + (size_t)row * NPTS + (size_t)chunk * CHUNK);
    float lsum = 0.f;
    #pragma unroll
    for (int i = 0; i < CHUNK / 4 / 256; i++) {       // 8 iterations
        v4f v = __builtin_nontemporal_load(p4 + i * 256 + tid);
        float c0 = clipp(v.x), c1 = clipp(v.y), c2 = clipp(v.z), c3 = clipp(v.w);
        lsum += (c0 + c1) + (c2 + c3);
        float mx = fmaxf(fmaxf(c0, c1), fmaxf(c2, c3));
        if (mx >= 0.99f) {                             // rare path
            int bi = chunk * CHUNK + (i * 256 + tid) * 4;
            float c4[4] = {c0, c1, c2, c3};
            #pragma unroll
            for (int j = 0; j < 4; j++) {
                if (c4[j] >= 0.99f) {
                    int p_ = atomicAdd(&lcnt, 1);
                    if (p_ < CCAP)
                        cb[p_] = (((unsigned long long)__float_as_uint(c4[j])) << 32)
                               | (unsigned)~(bi + j);
                }
            }
        }
    }
    #pragma unroll
    for (int off = 32; off; off >>= 1) lsum += __shfl_down(lsum, off);
    if ((tid & 63) == 0) wred[tid >> 6] = lsum;
    __syncthreads();
    if (tid == 0) {
        ws[WSO_PSUM + blockIdx.x] = (wred[0] + wred[1]) + (wred[2] + wred[3]);
        ((int*)ws)[WSO_CCNT + blockIdx.x] = min(lcnt, CCAP);
    }
}

// ---------------------------------------------------------------------------
// kB: per-row exact top-128/top-64 SETS + weighted moments + FUSED 64-lane
// element-parallel tournament Jacobi (lane (i,j) owns A[i][j]; 4 disjoint
// pivot pairs per round commute exactly; 6 sweeps x 7 rounds).
__global__ __launch_bounds__(256) void kB_select(
    const float* __restrict__ points, float* __restrict__ ws)
{
    __shared__ unsigned long long cand[CHUNKS * CCAP];  // 2048 -> 16 KB
    __shared__ unsigned long long comp[256];
    __shared__ int   hist[1024];
    __shared__ int   counts_s[CHUNKS];
    __shared__ int   ccnt_s, bt_s;
    __shared__ float sw[128];
    __shared__ float pc[128][9];                        // col 8 == 1.0f
    __shared__ float sred[44][4];
    __shared__ float slotm[44];
    __shared__ float wpart[2];
    __shared__ float covm[64];

    const int row = blockIdx.x;
    const int tid = threadIdx.x;

    if (tid < CHUNKS) counts_s[tid] = ((const int*)ws)[WSO_CCNT + row * CHUNKS + tid];
    if (tid == 0) { ccnt_s = 0; bt_s = 0; }
    #pragma unroll
    for (int k = 0; k < 4; k++) hist[tid * 4 + k] = 0;
    __syncthreads();

    // fixed-stride gather + histogram (slot = chunk*CCAP + t, CCAP=256 -> shifts)
    const unsigned long long* cb = (const unsigned long long*)ws;
    #pragma unroll
    for (int r = 0; r < CHUNKS; r++) {
        int s = r * 256 + tid;
        int c = s >> 8, t = s & 255;
        unsigned long long k = 0ull;
        if (t < counts_s[c]) {
            k = cb[((size_t)(row * CHUNKS + c) << 8) + t];
            atomicAdd(&hist[cand_bin(__uint_as_float((unsigned)(k >> 32)))], 1);
        }
        cand[s] = k;
    }
    __syncthreads();

    // threshold bin via one wave: suffix-scan 64 groups of 16 bins
    if (tid < 64) {
        int h[16]; int g = 0;
        #pragma unroll
        for (int k = 0; k < 16; k++) { h[k] = hist[tid * 16 + k]; g += h[k]; }
        int s = g;
        #pragma unroll
        for (int off = 1; off < 64; off <<= 1) {
            int o = __shfl_down(s, off);
            if (tid + off < 64) s += o;
        }
        int Snext = __shfl_down(s, 1);
        if (tid == 63) Snext = 0;
        if (s >= 128 && Snext < 128) {   // exactly one lane
            int acc = Snext, bt = tid * 16;
            #pragma unroll
            for (int k = 15; k >= 0; k--) {
                acc += h[k];
                if (acc >= 128) { bt = tid * 16 + k; break; }
            }
            bt_s = bt;
        }
    }
    __syncthreads();

    // compact survivors (bin >= bt); m in [128, ~140]
    const int bt = bt_s;
    #pragma unroll
    for (int r = 0; r < CHUNKS; r++) {
        unsigned long long k = cand[r * 256 + tid];
        if (k && cand_bin(__uint_as_float((unsigned)(k >> 32))) >= bt) {
            int p_ = atomicAdd(&ccnt_s, 1);
            if (p_ < 256) comp[p_] = k;
        }
    }
    __syncthreads();
    const int m = min(ccnt_s, 256);

    if (tid < 128) {
        sw[tid] = 0.f;
        #pragma unroll
        for (int j = 0; j < 9; j++) pc[tid][j] = (j == 8) ? 1.f : 0.f;
    }
    if (tid < 64) {
        ws[WSO_T64V + (size_t)row * 64 + tid] = 0.f;
        ((int*)ws)[WSO_T64I + (size_t)row * 64 + tid] = 0;
    }
    // rank of each survivor vs all m keys (broadcast LDS reads, unique keys)
    unsigned long long ki = (tid < m) ? comp[tid] : 0ull;
    int rank = 0;
    for (int j = 0; j < m; j++) rank += (comp[j] > ki) ? 1 : 0;
    __syncthreads();

    // scatter by rank: slots 0..127 = exact top-128 (rank order = lax.top_k order)
    if (tid < m && rank < 128) {
        float v = __uint_as_float((unsigned)(ki >> 32));
        unsigned idx = ~(unsigned)(ki & 0xFFFFFFFFu);
        sw[rank] = v;
        const float4* pt = (const float4*)(points + (size_t)idx * 8);
        float4 q0 = pt[0], q1 = pt[1];
        pc[rank][0] = q0.x; pc[rank][1] = q0.y; pc[rank][2] = q0.z; pc[rank][3] = q0.w;
        pc[rank][4] = q1.x; pc[rank][5] = q1.y; pc[rank][6] = q1.z; pc[rank][7] = q1.w;
        if (rank < 64) {
            ws[WSO_T64V + (size_t)row * 64 + rank] = v;
            ((int*)ws)[WSO_T64I + (size_t)row * 64 + rank] = (int)idx;
        }
    }
    __syncthreads();

    if (tid < 128) {
        float ww = sw[tid];
        #pragma unroll
        for (int off = 32; off; off >>= 1) ww += __shfl_down(ww, off);
        if ((tid & 63) == 0) wpart[tid >> 6] = ww;
    }
    // moments: 44 slots x 4 partials (tid < 176)
    if (tid < 176) {
        int s = tid >> 2, part = tid & 3;
        int i_, j_;
        if (s < 36) {
            int rem = s; i_ = 0;
            while (rem >= 8 - i_) { rem -= 8 - i_; i_++; }
            j_ = i_ + rem;
        } else { i_ = s - 36; j_ = 8; }
        float acc = 0.f;
        for (int k = part * 32; k < part * 32 + 32; k++)
            acc += sw[k] * pc[k][i_] * pc[k][j_];
        sred[s][part] = acc;
    }
    __syncthreads();
    if (tid < 44) slotm[tid] = (sred[tid][0] + sred[tid][1]) + (sred[tid][2] + sred[tid][3]);
    __syncthreads();

    if (tid < 64) {
        float w128 = fmaxf(wpart[0] + wpart[1], 1e-6f);
        int i_ = tid >> 3, j_ = tid & 7;
        int a_ = min(i_, j_), b_ = max(i_, j_);
        int s3 = 8 * a_ - (a_ * (a_ - 1)) / 2 + (b_ - a_);
        covm[tid] = slotm[s3] / w128 - (slotm[36 + i_] / w128) * (slotm[36 + j_] / w128);
    }
    __syncthreads();

    // housekeeping on wave 1 (wave 0 starts the eigensolve immediately)
    if (tid == 64) {
        ws[WSO_ANORM + row] = fmaxf(wpart[0], 1e-6f);
        float s = 0.f;
        for (int c = 0; c < CHUNKS; c++) s += ws[WSO_PSUM + row * CHUNKS + c];
        ws[WSO_SUMP + row] = s;
        ((unsigned*)ws)[WSO_PMAXP + row] = 0u;          // init for k3a atomicMax
        ((unsigned*)ws)[WSO_PMAXN + row] = 0u;
        ((int*)ws)[WSO_NEARCNT + row * 2 + 0] = 0;      // init near-max lists
        ((int*)ws)[WSO_NEARCNT + row * 2 + 1] = 0;
    }

    // ---- fused element-parallel Jacobi (wave 0; lane = i*8+j owns A[i][j]) ----
    if (tid < 64) {
        const int i = tid >> 3, j = tid & 7;
        float a = covm[tid];
        float v = (i == j) ? 1.f : 0.f;
        // round-robin tournament pairings; octal digit i = partner(i)
        const unsigned PR[7] = {023456701u, 001234567u, 050712346u, 034067125u,
                                012305674u, 067120453u, 045671032u};
        #pragma unroll 1
        for (int sweep = 0; sweep < 6; sweep++) {
            #pragma unroll
            for (int r = 0; r < 7; r++) {
                const unsigned pk = PR[r];
                const int rp = (pk >> (3 * i)) & 7;       // row-pair partner
                const int cp = (pk >> (3 * j)) & 7;       // col-pair partner
                const int pr = min(i, rp), qr = max(i, rp);
                float app = __shfl(a, pr * 9);
                float aqq = __shfl(a, qr * 9);
                float apq = __shfl(a, pr * 8 + qr);
                float tau = 0.5f * (aqq - app);
                float den = fabsf(tau) + sqrtf(fmaf(tau, tau, apq * apq));
                float t = __fdividef(apq, den + 1e-38f);  // apq==0 -> identity
                t = (tau < 0.f) ? -t : t;
                float cr = rsqrtf(fmaf(t, t, 1.f));
                float sr = t * cr;
                float cc = __shfl(cr, j * 9);
                float sc = __shfl(sr, j * 9);
                float oth = __shfl(a, rp * 8 + j);        // row phase (J^T A)
                a = fmaf((i < rp) ? -sr : sr, oth, cr * a);
                float oth2 = __shfl(a, i * 8 + cp);       // col phase (A J)
                a = fmaf((j < cp) ? -sc : sc, oth2, cc * a);
                float ov = __shfl(v, i * 8 + cp);
                v = fmaf((j < cp) ? -sc : sc, ov, cc * v);
            }
        }
        float d[8];
        #pragma unroll
        for (int k = 0; k < 8; k++) d[k] = __shfl(a, k * 9);
        float e0 = d[0]; int i0 = 0;
        #pragma unroll
        for (int k = 1; k < 8; k++) if (d[k] < e0) { e0 = d[k]; i0 = k; }
        float e1 = 3.4e38f;
        #pragma unroll
        for (int k = 0; k < 8; k++) if (k != i0 && d[k] < e1) e1 = d[k];
        if (tid == 0) {
            ws[WSO_PLANE + row] = e0;
            ws[WSO_FACET + row] = e0 / (e1 + 1e-6f);
        }
        if (j == i0) ws[WSO_NRM + (size_t)row * 8 + i] = v;   // V[:,i0]
        // eigenvector sign arbitrary: boundary = min(b_pos, b_neg) is sign-invariant
    }
}

// ---------------------------------------------------------------------------
// k3a: row maxes of proj/-proj AND near-max candidate collection in ONE pass.
// d >= globalmax-0.05 implies d >= blockmax-0.05: per-block filtered list is
// a superset of what the inactive term needs.
constexpr int R3 = 4;
constexpr int P3 = 2048;
__global__ __launch_bounds__(256) void k3a_max(
    const float* __restrict__ points, float* __restrict__ ws)
{
    __shared__ float redp[4][R3], redn[4][R3];
    __shared__ float bmax[2 * R3];
    const int tid = threadIdx.x;
    const int r0  = blockIdx.y * R3;
    const int n0  = blockIdx.x * P3;
    float nr[R3][8];
    #pragma unroll
    for (int r = 0; r < R3; r++)
        #pragma unroll
        for (int j = 0; j < 8; j++)
            nr[r][j] = ws[WSO_NRM + (size_t)(r0 + r) * 8 + j];
    float dsv[P3 / 256][R3];
    float mp[R3], mn[R3];
    #pragma unroll
    for (int r = 0; r < R3; r++) { mp[r] = -3.4e38f; mn[r] = -3.4e38f; }
    const float4* pb = (const float4*)points + (size_t)n0 * 2;
    #pragma unroll
    for (int it = 0; it < P3 / 256; it++) {
        int t2 = (it * 256 + tid) * 2;
        float4 q0 = pb[t2], q1 = pb[t2 + 1];
        #pragma unroll
        for (int r = 0; r < R3; r++) {
            float d = dot8(q0, q1, nr[r]);
            dsv[it][r] = d;
            mp[r] = fmaxf(mp[r], d);
            mn[r] = fmaxf(mn[r], -d);
        }
    }
    #pragma unroll
    for (int r = 0; r < R3; r++) {
        #pragma unroll
        for (int off = 32; off; off >>= 1) {
            mp[r] = fmaxf(mp[r], __shfl_xor(mp[r], off));
            mn[r] = fmaxf(mn[r], __shfl_xor(mn[r], off));
        }
    }
    if ((tid & 63) == 0) {
        int wv = tid >> 6;
        #pragma unroll
        for (int r = 0; r < R3; r++) { redp[wv][r] = mp[r]; redn[wv][r] = mn[r]; }
    }
    __syncthreads();
    if (tid < 2 * R3) {
        int r = tid & (R3 - 1);
        bool neg = tid >= R3;
        float m = neg
            ? fmaxf(fmaxf(redn[0][r], redn[1][r]), fmaxf(redn[2][r], redn[3][r]))
            : fmaxf(fmaxf(redp[0][r], redp[1][r]), fmaxf(redp[2][r], redp[3][r]));
        bmax[tid] = m;
        unsigned* wsu = (unsigned*)ws;
        atomicMax(&wsu[(neg ? WSO_PMAXN : WSO_PMAXP) + r0 + r], f2mono(m));
    }
    __syncthreads();
    float bmx[R3], bmn[R3];
    #pragma unroll
    for (int r = 0; r < R3; r++) { bmx[r] = bmax[r]; bmn[r] = bmax[R3 + r]; }

    // near-max candidates -> global per-row-sign lists (rare)
    int* ncnt = (int*)ws + WSO_NEARCNT;
    unsigned long long* nbuf = (unsigned long long*)ws + WSO_NEAR / 2;
    #pragma unroll
    for (int it = 0; it < P3 / 256; it++) {
        int nn = n0 + it * 256 + tid;
        #pragma unroll
        for (int r = 0; r < R3; r++) {
            float d = dsv[it][r];
            if (d >= bmx[r] - 0.05f) {
                int p_ = atomicAdd(&ncnt[(r0 + r) * 2 + 0], 1);
                if (p_ < NEARCAP)
                    nbuf[(size_t)((r0 + r) * 2 + 0) * NEARCAP + p_] =
                        (((unsigned long long)__float_as_uint(d)) << 32) | (unsigned)nn;
            }
            if (-d >= bmn[r] - 0.05f) {
                int p_ = atomicAdd(&ncnt[(r0 + r) * 2 + 1], 1);
                if (p_ < NEARCAP)
                    nbuf[(size_t)((r0 + r) * 2 + 1) * NEARCAP + p_] =
                        (((unsigned long long)__float_as_uint(-d)) << 32) | (unsigned)nn;
            }
        }
    }
}

// ---------------------------------------------------------------------------
// k3cd: fused inactive term (near-max lists, ~36 entries/row-sign) + active
// term (top-64) + final combine. support = relu(signed.max)^2 == 0 -> omitted.
__global__ __launch_bounds__(64) void k3cd_final(
    const float* __restrict__ points, const float* __restrict__ prob,
    const float* __restrict__ ws, float* __restrict__ out)
{
    const int row = blockIdx.x;
    const int t   = threadIdx.x;
    const unsigned* wsu = (const unsigned*)ws;
    __shared__ float nl[8];
    if (t < 8) nl[t] = ws[WSO_NRM + (size_t)row * 8 + t];
    __syncthreads();

    const float pmaxp = mono2f(wsu[WSO_PMAXP + row]);
    const float pmaxn = mono2f(wsu[WSO_PMAXN + row]);

    // active term over top-64
    float w   = ws[WSO_T64V + (size_t)row * 64 + t];
    int   idx = ((const int*)ws)[WSO_T64I + (size_t)row * 64 + t];
    const float4* pt = (const float4*)(points + (size_t)idx * 8);
    float4 q0 = pt[0], q1 = pt[1];
    float d = dot8(q0, q1, nl);
    float sp = d - pmaxp, sn = -d - pmaxn;
    float ap = w * sp * sp;
    float an = w * sn * sn;

    // inactive term from near-max lists
    const int* ncnt = (const int*)ws + WSO_NEARCNT;
    const unsigned long long* nbuf = (const unsigned long long*)ws + WSO_NEAR / 2;
    float ip = 0.f, in_ = 0.f;
    int cp = min(ncnt[row * 2 + 0], NEARCAP);
    int cn = min(ncnt[row * 2 + 1], NEARCAP);
    for (int i = t; i < cp; i += 64) {
        unsigned long long e = nbuf[(size_t)(row * 2 + 0) * NEARCAP + i];
        float dv = __uint_as_float((unsigned)(e >> 32));
        float tp = 0.05f + (dv - pmaxp);
        if (tp > 0.f) {
            float w2 = 1.0f - clipp(prob[(size_t)row * NPTS + (unsigned)(e & 0xFFFFFFFFu)]);
            ip = fmaf(w2 * tp, tp, ip);
        }
    }
    for (int i = t; i < cn; i += 64) {
        unsigned long long e = nbuf[(size_t)(row * 2 + 1) * NEARCAP + i];
        float dv = __uint_as_float((unsigned)(e >> 32));
        float tn = 0.05f + (dv - pmaxn);
        if (tn > 0.f) {
            float w2 = 1.0f - clipp(prob[(size_t)row * NPTS + (unsigned)(e & 0xFFFFFFFFu)]);
            in_ = fmaf(w2 * tn, tn, in_);
        }
    }
    #pragma unroll
    for (int off = 32; off; off >>= 1) {
        ap  += __shfl_down(ap, off);
        an  += __shfl_down(an, off);
        ip  += __shfl_down(ip, off);
        in_ += __shfl_down(in_, off);
    }
    if (t == 0) {
        float anorm = ws[WSO_ANORM + row];
        float sump  = ws[WSO_SUMP + row];
        float inorm = fmaxf((float)NPTS - sump, 1e-6f);
        float bp = (ap / anorm) + 0.35f * (ip / inorm);
        float bn = (an / anorm) + 0.35f * (in_ / inorm);
        float bd = (bp <= bn) ? bp : bn;
        float def = fmaxf(26.0f - sump, 0.f);
        out[row] = ws[WSO_PLANE + row] + 8.0f * ws[WSO_FACET + row]
                 + 4.0f * bd + 25.0f * def * def;
    }
}

// ---------------------------------------------------------------------------
extern "C" void kernel_launch(void* const* d_in, const int* in_sizes, int n_in,
                              void* d_out, int out_size, void* d_ws, size_t ws_size,
                              hipStream_t stream) {
    const float* prob   = (const float*)d_in[0];  // (256, 65536) f32
    const float* points = (const float*)d_in[1];  // (65536, 8) f32
    float* out = (float*)d_out;                   // (256,) f32
    float* ws  = (float*)d_ws;                    // ~5 MB used

    kA_stream<<<NBLK, 256, 0, stream>>>(prob, ws);
    kB_select<<<B, 256, 0, stream>>>(points, ws);
    dim3 g3(NPTS / P3, B / R3);
    k3a_max<<<g3, 256, 0, stream>>>(points, ws);
    k3cd_final<<<B, 64, 0, stream>>>(points, prob, ws, out);
}

// Round 9
// 146.370 us; speedup vs baseline: 1.7387x; 1.0559x over previous
//
#include <hip/hip_runtime.h>
#include <cstdint>
#include <cstddef>

// Problem constants
constexpr int NPTS   = 65536;
constexpr int B      = 256;
constexpr int CHUNKS = 8;              // chunks per row (stream phase)
constexpr int CHUNK  = NPTS / CHUNKS;  // 8192 elements
constexpr int CCAP   = 256;            // per-chunk cap (mean 82, sigma 9 -> +19 sigma)
constexpr int NBLK   = B * CHUNKS;     // 2048 stream blocks
constexpr int NEARCAP = 128;           // near-max list cap per row-sign (mean ~36)

// Workspace layout (word offsets; u64 regions first => 8-byte aligned)
constexpr size_t WSO_CBUF    = 0;                                      // NBLK*CCAP u64
constexpr size_t WSO_NEAR    = WSO_CBUF + (size_t)NBLK * CCAP * 2;     // 2*B*NEARCAP u64
constexpr size_t WSO_NEARCNT = WSO_NEAR + (size_t)2 * B * NEARCAP * 2; // 2*B ints
constexpr size_t WSO_PSUM    = WSO_NEARCNT + 2 * B;                    // NBLK floats
constexpr size_t WSO_CCNT    = WSO_PSUM + NBLK;                        // NBLK ints
constexpr size_t WSO_PLANE   = WSO_CCNT + NBLK;                        // B floats
constexpr size_t WSO_FACET   = WSO_PLANE + B;                          // B floats
constexpr size_t WSO_NRM     = WSO_FACET + B;                          // B*8 floats
constexpr size_t WSO_SUMP    = WSO_NRM + (size_t)B * 8;                // B floats
constexpr size_t WSO_ANORM   = WSO_SUMP + B;                           // B floats
constexpr size_t WSO_T64V    = WSO_ANORM + B;                          // B*64 floats
constexpr size_t WSO_T64I    = WSO_T64V + (size_t)B * 64;              // B*64 ints
constexpr size_t WSO_PMAXP   = WSO_T64I + (size_t)B * 64;              // B uints
constexpr size_t WSO_PMAXN   = WSO_PMAXP + B;                          // B uints
// total ~5 MB

__device__ __forceinline__ float clipp(float x) {
    return fminf(fmaxf(x, 1e-5f), 0.99999f);
}
__device__ __forceinline__ unsigned f2mono(float f) {
    unsigned u = __float_as_uint(f);
    return (u & 0x80000000u) ? ~u : (u | 0x80000000u);
}
__device__ __forceinline__ float mono2f(unsigned e) {
    return __uint_as_float((e & 0x80000000u) ? (e ^ 0x80000000u) : ~e);
}
__device__ __forceinline__ int cand_bin(float v) {
    int b = (int)((v - 0.99f) * 102400.0f);   // 1024 bins over [0.99, 1.0)
    return min(max(b, 0), 1023);
}
__device__ __forceinline__ float dot8(float4 a, float4 b, const float* n) {
    float d = a.x * n[0];
    d = fmaf(a.y, n[1], d); d = fmaf(a.z, n[2], d); d = fmaf(a.w, n[3], d);
    d = fmaf(b.x, n[4], d); d = fmaf(b.y, n[5], d); d = fmaf(b.z, n[6], d);
    d = fmaf(b.w, n[7], d);
    return d;
}

// ---------------------------------------------------------------------------
// kA: streaming pass over the 64 MB prob matrix at HBM rate.
// 2048 blocks x 256 threads, 32 elements/thread. All 8 float4 loads are
// pre-issued into registers (8 KB in flight per wave) BEFORE any processing
// — the processing path has LDS atomics that otherwise cap the compiler at
// ~1 outstanding load, leaving the stream latency-exposed.
__global__ __launch_bounds__(256) void kA_stream(
    const float* __restrict__ prob, float* __restrict__ ws)
{
    __shared__ float wred[4];
    __shared__ int lcnt;
    const int tid   = threadIdx.x;
    const int row   = blockIdx.x >> 3;
    const int chunk = blockIdx.x & 7;
    if (tid == 0) lcnt = 0;
    __syncthreads();

    unsigned long long* cb = (unsigned long long*)ws + (size_t)blockIdx.x * CCAP;
    const float4* p4 = (const float4*)(prob + (size_t)row * NPTS + (size_t)chunk * CHUNK);

    float4 v[8];
    #pragma unroll
    for (int i = 0; i < 8; i++) v[i] = p4[i * 256 + tid];   // all loads in flight

    float lsum = 0.f;
    #pragma unroll
    for (int i = 0; i < 8; i++) {
        float c0 = clipp(v[i].x), c1 = clipp(v[i].y), c2 = clipp(v[i].z), c3 = clipp(v[i].w);
        lsum += (c0 + c1) + (c2 + c3);
        float mx = fmaxf(fmaxf(c0, c1), fmaxf(c2, c3));
        if (mx >= 0.99f) {
            int bi = chunk * CHUNK + (i * 256 + tid) * 4;
            float c4[4] = {c0, c1, c2, c3};
            #pragma unroll
            for (int j = 0; j < 4; j++) {
                if (c4[j] >= 0.99f) {
                    int p_ = atomicAdd(&lcnt, 1);
                    if (p_ < CCAP)
                        cb[p_] = (((unsigned long long)__float_as_uint(c4[j])) << 32)
                               | (unsigned)~(bi + j);
                }
            }
        }
    }
    #pragma unroll
    for (int off = 32; off; off >>= 1) lsum += __shfl_down(lsum, off);
    if ((tid & 63) == 0) wred[tid >> 6] = lsum;
    __syncthreads();
    if (tid == 0) {
        ws[WSO_PSUM + blockIdx.x] = (wred[0] + wred[1]) + (wred[2] + wred[3]);
        ((int*)ws)[WSO_CCNT + blockIdx.x] = min(lcnt, CCAP);
    }
}

// ---------------------------------------------------------------------------
// kB: per-row exact top-128/top-64 SETS + weighted moments + FUSED 64-lane
// element-parallel tournament Jacobi (lane (i,j) owns A[i][j]; 4 disjoint
// pivot pairs per round commute exactly; 6 sweeps x 7 rounds).
__global__ __launch_bounds__(256) void kB_select(
    const float* __restrict__ points, float* __restrict__ ws)
{
    __shared__ unsigned long long cand[CHUNKS * CCAP];  // 2048 -> 16 KB
    __shared__ unsigned long long comp[256];
    __shared__ int   hist[1024];
    __shared__ int   counts_s[CHUNKS];
    __shared__ int   ccnt_s, bt_s;
    __shared__ float sw[128];
    __shared__ float pc[128][9];                        // col 8 == 1.0f
    __shared__ float sred[44][4];
    __shared__ float slotm[44];
    __shared__ float wpart[2];
    __shared__ float covm[64];

    const int row = blockIdx.x;
    const int tid = threadIdx.x;

    if (tid < CHUNKS) counts_s[tid] = ((const int*)ws)[WSO_CCNT + row * CHUNKS + tid];
    if (tid == 0) { ccnt_s = 0; bt_s = 0; }
    #pragma unroll
    for (int k = 0; k < 4; k++) hist[tid * 4 + k] = 0;
    __syncthreads();

    // fixed-stride gather + histogram (slot = chunk*CCAP + t, CCAP=256 -> shifts)
    const unsigned long long* cb = (const unsigned long long*)ws;
    #pragma unroll
    for (int r = 0; r < CHUNKS; r++) {
        int s = r * 256 + tid;
        int c = s >> 8, t = s & 255;
        unsigned long long k = 0ull;
        if (t < counts_s[c]) {
            k = cb[((size_t)(row * CHUNKS + c) << 8) + t];
            atomicAdd(&hist[cand_bin(__uint_as_float((unsigned)(k >> 32)))], 1);
        }
        cand[s] = k;
    }
    __syncthreads();

    // threshold bin via one wave: suffix-scan 64 groups of 16 bins
    if (tid < 64) {
        int h[16]; int g = 0;
        #pragma unroll
        for (int k = 0; k < 16; k++) { h[k] = hist[tid * 16 + k]; g += h[k]; }
        int s = g;
        #pragma unroll
        for (int off = 1; off < 64; off <<= 1) {
            int o = __shfl_down(s, off);
            if (tid + off < 64) s += o;
        }
        int Snext = __shfl_down(s, 1);
        if (tid == 63) Snext = 0;
        if (s >= 128 && Snext < 128) {   // exactly one lane
            int acc = Snext, bt = tid * 16;
            #pragma unroll
            for (int k = 15; k >= 0; k--) {
                acc += h[k];
                if (acc >= 128) { bt = tid * 16 + k; break; }
            }
            bt_s = bt;
        }
    }
    __syncthreads();

    // compact survivors (bin >= bt); m in [128, ~140]
    const int bt = bt_s;
    #pragma unroll
    for (int r = 0; r < CHUNKS; r++) {
        unsigned long long k = cand[r * 256 + tid];
        if (k && cand_bin(__uint_as_float((unsigned)(k >> 32))) >= bt) {
            int p_ = atomicAdd(&ccnt_s, 1);
            if (p_ < 256) comp[p_] = k;
        }
    }
    __syncthreads();
    const int m = min(ccnt_s, 256);

    if (tid < 128) {
        sw[tid] = 0.f;
        #pragma unroll
        for (int j = 0; j < 9; j++) pc[tid][j] = (j == 8) ? 1.f : 0.f;
    }
    if (tid < 64) {
        ws[WSO_T64V + (size_t)row * 64 + tid] = 0.f;
        ((int*)ws)[WSO_T64I + (size_t)row * 64 + tid] = 0;
    }
    // rank of each survivor vs all m keys (broadcast LDS reads, unique keys)
    unsigned long long ki = (tid < m) ? comp[tid] : 0ull;
    int rank = 0;
    for (int j = 0; j < m; j++) rank += (comp[j] > ki) ? 1 : 0;
    __syncthreads();

    // scatter by rank: slots 0..127 = exact top-128 (rank order = lax.top_k order)
    if (tid < m && rank < 128) {
        float v = __uint_as_float((unsigned)(ki >> 32));
        unsigned idx = ~(unsigned)(ki & 0xFFFFFFFFu);
        sw[rank] = v;
        const float4* pt = (const float4*)(points + (size_t)idx * 8);
        float4 q0 = pt[0], q1 = pt[1];
        pc[rank][0] = q0.x; pc[rank][1] = q0.y; pc[rank][2] = q0.z; pc[rank][3] = q0.w;
        pc[rank][4] = q1.x; pc[rank][5] = q1.y; pc[rank][6] = q1.z; pc[rank][7] = q1.w;
        if (rank < 64) {
            ws[WSO_T64V + (size_t)row * 64 + rank] = v;
            ((int*)ws)[WSO_T64I + (size_t)row * 64 + rank] = (int)idx;
        }
    }
    __syncthreads();

    if (tid < 128) {
        float ww = sw[tid];
        #pragma unroll
        for (int off = 32; off; off >>= 1) ww += __shfl_down(ww, off);
        if ((tid & 63) == 0) wpart[tid >> 6] = ww;
    }
    // moments: 44 slots x 4 partials (tid < 176)
    if (tid < 176) {
        int s = tid >> 2, part = tid & 3;
        int i_, j_;
        if (s < 36) {
            int rem = s; i_ = 0;
            while (rem >= 8 - i_) { rem -= 8 - i_; i_++; }
            j_ = i_ + rem;
        } else { i_ = s - 36; j_ = 8; }
        float acc = 0.f;
        for (int k = part * 32; k < part * 32 + 32; k++)
            acc += sw[k] * pc[k][i_] * pc[k][j_];
        sred[s][part] = acc;
    }
    __syncthreads();
    if (tid < 44) slotm[tid] = (sred[tid][0] + sred[tid][1]) + (sred[tid][2] + sred[tid][3]);
    __syncthreads();

    if (tid < 64) {
        float w128 = fmaxf(wpart[0] + wpart[1], 1e-6f);
        int i_ = tid >> 3, j_ = tid & 7;
        int a_ = min(i_, j_), b_ = max(i_, j_);
        int s3 = 8 * a_ - (a_ * (a_ - 1)) / 2 + (b_ - a_);
        covm[tid] = slotm[s3] / w128 - (slotm[36 + i_] / w128) * (slotm[36 + j_] / w128);
    }
    __syncthreads();

    // housekeeping on wave 1 (wave 0 starts the eigensolve immediately)
    if (tid == 64) {
        ws[WSO_ANORM + row] = fmaxf(wpart[0], 1e-6f);
        float s = 0.f;
        for (int c = 0; c < CHUNKS; c++) s += ws[WSO_PSUM + row * CHUNKS + c];
        ws[WSO_SUMP + row] = s;
        ((unsigned*)ws)[WSO_PMAXP + row] = 0u;          // init for k3a atomicMax
        ((unsigned*)ws)[WSO_PMAXN + row] = 0u;
        ((int*)ws)[WSO_NEARCNT + row * 2 + 0] = 0;      // init near-max lists
        ((int*)ws)[WSO_NEARCNT + row * 2 + 1] = 0;
    }

    // ---- fused element-parallel Jacobi (wave 0; lane = i*8+j owns A[i][j]) ----
    if (tid < 64) {
        const int i = tid >> 3, j = tid & 7;
        float a = covm[tid];
        float v = (i == j) ? 1.f : 0.f;
        // round-robin tournament pairings; octal digit i = partner(i)
        const unsigned PR[7] = {023456701u, 001234567u, 050712346u, 034067125u,
                                012305674u, 067120453u, 045671032u};
        #pragma unroll 1
        for (int sweep = 0; sweep < 6; sweep++) {
            #pragma unroll
            for (int r = 0; r < 7; r++) {
                const unsigned pk = PR[r];
                const int rp = (pk >> (3 * i)) & 7;       // row-pair partner
                const int cp = (pk >> (3 * j)) & 7;       // col-pair partner
                const int pr = min(i, rp), qr = max(i, rp);
                float app = __shfl(a, pr * 9);
                float aqq = __shfl(a, qr * 9);
                float apq = __shfl(a, pr * 8 + qr);
                float tau = 0.5f * (aqq - app);
                float den = fabsf(tau) + sqrtf(fmaf(tau, tau, apq * apq));
                float t = __fdividef(apq, den + 1e-38f);  // apq==0 -> identity
                t = (tau < 0.f) ? -t : t;
                float cr = rsqrtf(fmaf(t, t, 1.f));
                float sr = t * cr;
                float cc = __shfl(cr, j * 9);
                float sc = __shfl(sr, j * 9);
                float oth = __shfl(a, rp * 8 + j);        // row phase (J^T A)
                a = fmaf((i < rp) ? -sr : sr, oth, cr * a);
                float oth2 = __shfl(a, i * 8 + cp);       // col phase (A J)
                a = fmaf((j < cp) ? -sc : sc, oth2, cc * a);
                float ov = __shfl(v, i * 8 + cp);
                v = fmaf((j < cp) ? -sc : sc, ov, cc * v);
            }
        }
        float d[8];
        #pragma unroll
        for (int k = 0; k < 8; k++) d[k] = __shfl(a, k * 9);
        float e0 = d[0]; int i0 = 0;
        #pragma unroll
        for (int k = 1; k < 8; k++) if (d[k] < e0) { e0 = d[k]; i0 = k; }
        float e1 = 3.4e38f;
        #pragma unroll
        for (int k = 0; k < 8; k++) if (k != i0 && d[k] < e1) e1 = d[k];
        if (tid == 0) {
            ws[WSO_PLANE + row] = e0;
            ws[WSO_FACET + row] = e0 / (e1 + 1e-6f);
        }
        if (j == i0) ws[WSO_NRM + (size_t)row * 8 + i] = v;   // V[:,i0]
        // eigenvector sign arbitrary: boundary = min(b_pos, b_neg) is sign-invariant
    }
}

// ---------------------------------------------------------------------------
// k3a: row maxes of proj/-proj AND near-max candidate collection in ONE pass.
// d >= globalmax-0.05 implies d >= blockmax-0.05: per-block filtered list is
// a superset of what the inactive term needs.
constexpr int R3 = 4;
constexpr int P3 = 2048;
__global__ __launch_bounds__(256) void k3a_max(
    const float* __restrict__ points, float* __restrict__ ws)
{
    __shared__ float redp[4][R3], redn[4][R3];
    __shared__ float bmax[2 * R3];
    const int tid = threadIdx.x;
    const int r0  = blockIdx.y * R3;
    const int n0  = blockIdx.x * P3;
    float nr[R3][8];
    #pragma unroll
    for (int r = 0; r < R3; r++)
        #pragma unroll
        for (int j = 0; j < 8; j++)
            nr[r][j] = ws[WSO_NRM + (size_t)(r0 + r) * 8 + j];
    float dsv[P3 / 256][R3];
    float mp[R3], mn[R3];
    #pragma unroll
    for (int r = 0; r < R3; r++) { mp[r] = -3.4e38f; mn[r] = -3.4e38f; }
    const float4* pb = (const float4*)points + (size_t)n0 * 2;
    #pragma unroll
    for (int it = 0; it < P3 / 256; it++) {
        int t2 = (it * 256 + tid) * 2;
        float4 q0 = pb[t2], q1 = pb[t2 + 1];
        #pragma unroll
        for (int r = 0; r < R3; r++) {
            float d = dot8(q0, q1, nr[r]);
            dsv[it][r] = d;
            mp[r] = fmaxf(mp[r], d);
            mn[r] = fmaxf(mn[r], -d);
        }
    }
    #pragma unroll
    for (int r = 0; r < R3; r++) {
        #pragma unroll
        for (int off = 32; off; off >>= 1) {
            mp[r] = fmaxf(mp[r], __shfl_xor(mp[r], off));
            mn[r] = fmaxf(mn[r], __shfl_xor(mn[r], off));
        }
    }
    if ((tid & 63) == 0) {
        int wv = tid >> 6;
        #pragma unroll
        for (int r = 0; r < R3; r++) { redp[wv][r] = mp[r]; redn[wv][r] = mn[r]; }
    }
    __syncthreads();
    if (tid < 2 * R3) {
        int r = tid & (R3 - 1);
        bool neg = tid >= R3;
        float m = neg
            ? fmaxf(fmaxf(redn[0][r], redn[1][r]), fmaxf(redn[2][r], redn[3][r]))
            : fmaxf(fmaxf(redp[0][r], redp[1][r]), fmaxf(redp[2][r], redp[3][r]));
        bmax[tid] = m;
        unsigned* wsu = (unsigned*)ws;
        atomicMax(&wsu[(neg ? WSO_PMAXN : WSO_PMAXP) + r0 + r], f2mono(m));
    }
    __syncthreads();
    float bmx[R3], bmn[R3];
    #pragma unroll
    for (int r = 0; r < R3; r++) { bmx[r] = bmax[r]; bmn[r] = bmax[R3 + r]; }

    // near-max candidates -> global per-row-sign lists (rare)
    int* ncnt = (int*)ws + WSO_NEARCNT;
    unsigned long long* nbuf = (unsigned long long*)ws + WSO_NEAR / 2;
    #pragma unroll
    for (int it = 0; it < P3 / 256; it++) {
        int nn = n0 + it * 256 + tid;
        #pragma unroll
        for (int r = 0; r < R3; r++) {
            float d = dsv[it][r];
            if (d >= bmx[r] - 0.05f) {
                int p_ = atomicAdd(&ncnt[(r0 + r) * 2 + 0], 1);
                if (p_ < NEARCAP)
                    nbuf[(size_t)((r0 + r) * 2 + 0) * NEARCAP + p_] =
                        (((unsigned long long)__float_as_uint(d)) << 32) | (unsigned)nn;
            }
            if (-d >= bmn[r] - 0.05f) {
                int p_ = atomicAdd(&ncnt[(r0 + r) * 2 + 1], 1);
                if (p_ < NEARCAP)
                    nbuf[(size_t)((r0 + r) * 2 + 1) * NEARCAP + p_] =
                        (((unsigned long long)__float_as_uint(-d)) << 32) | (unsigned)nn;
            }
        }
    }
}

// ---------------------------------------------------------------------------
// k3cd: fused inactive term (near-max lists, ~36 entries/row-sign) + active
// term (top-64) + final combine. support = relu(signed.max)^2 == 0 -> omitted.
__global__ __launch_bounds__(64) void k3cd_final(
    const float* __restrict__ points, const float* __restrict__ prob,
    const float* __restrict__ ws, float* __restrict__ out)
{
    const int row = blockIdx.x;
    const int t   = threadIdx.x;
    const unsigned* wsu = (const unsigned*)ws;
    __shared__ float nl[8];
    if (t < 8) nl[t] = ws[WSO_NRM + (size_t)row * 8 + t];
    __syncthreads();

    const float pmaxp = mono2f(wsu[WSO_PMAXP + row]);
    const float pmaxn = mono2f(wsu[WSO_PMAXN + row]);

    // active term over top-64
    float w   = ws[WSO_T64V + (size_t)row * 64 + t];
    int   idx = ((const int*)ws)[WSO_T64I + (size_t)row * 64 + t];
    const float4* pt = (const float4*)(points + (size_t)idx * 8);
    float4 q0 = pt[0], q1 = pt[1];
    float d = dot8(q0, q1, nl);
    float sp = d - pmaxp, sn = -d - pmaxn;
    float ap = w * sp * sp;
    float an = w * sn * sn;

    // inactive term from near-max lists
    const int* ncnt = (const int*)ws + WSO_NEARCNT;
    const unsigned long long* nbuf = (const unsigned long long*)ws + WSO_NEAR / 2;
    float ip = 0.f, in_ = 0.f;
    int cp = min(ncnt[row * 2 + 0], NEARCAP);
    int cn = min(ncnt[row * 2 + 1], NEARCAP);
    for (int i = t; i < cp; i += 64) {
        unsigned long long e = nbuf[(size_t)(row * 2 + 0) * NEARCAP + i];
        float dv = __uint_as_float((unsigned)(e >> 32));
        float tp = 0.05f + (dv - pmaxp);
        if (tp > 0.f) {
            float w2 = 1.0f - clipp(prob[(size_t)row * NPTS + (unsigned)(e & 0xFFFFFFFFu)]);
            ip = fmaf(w2 * tp, tp, ip);
        }
    }
    for (int i = t; i < cn; i += 64) {
        unsigned long long e = nbuf[(size_t)(row * 2 + 1) * NEARCAP + i];
        float dv = __uint_as_float((unsigned)(e >> 32));
        float tn = 0.05f + (dv - pmaxn);
        if (tn > 0.f) {
            float w2 = 1.0f - clipp(prob[(size_t)row * NPTS + (unsigned)(e & 0xFFFFFFFFu)]);
            in_ = fmaf(w2 * tn, tn, in_);
        }
    }
    #pragma unroll
    for (int off = 32; off; off >>= 1) {
        ap  += __shfl_down(ap, off);
        an  += __shfl_down(an, off);
        ip  += __shfl_down(ip, off);
        in_ += __shfl_down(in_, off);
    }
    if (t == 0) {
        float anorm = ws[WSO_ANORM + row];
        float sump  = ws[WSO_SUMP + row];
        float inorm = fmaxf((float)NPTS - sump, 1e-6f);
        float bp = (ap / anorm) + 0.35f * (ip / inorm);
        float bn = (an / anorm) + 0.35f * (in_ / inorm);
        float bd = (bp <= bn) ? bp : bn;
        float def = fmaxf(26.0f - sump, 0.f);
        out[row] = ws[WSO_PLANE + row] + 8.0f * ws[WSO_FACET + row]
                 + 4.0f * bd + 25.0f * def * def;
    }
}

// ---------------------------------------------------------------------------
extern "C" void kernel_launch(void* const* d_in, const int* in_sizes, int n_in,
                              void* d_out, int out_size, void* d_ws, size_t ws_size,
                              hipStream_t stream) {
    const float* prob   = (const float*)d_in[0];  // (256, 65536) f32
    const float* points = (const float*)d_in[1];  // (65536, 8) f32
    float* out = (float*)d_out;                   // (256,) f32
    float* ws  = (float*)d_ws;                    // ~5 MB used

    kA_stream<<<NBLK, 256, 0, stream>>>(prob, ws);
    kB_select<<<B, 256, 0, stream>>>(points, ws);
    dim3 g3(NPTS / P3, B / R3);
    k3a_max<<<g3, 256, 0, stream>>>(points, ws);
    k3cd_final<<<B, 64, 0, stream>>>(points, prob, ws, out);
}